// Round 13
// baseline (23.009 us; speedup 1.0000x reference)
//
#include <hip/hip_runtime.h>
#include <stdint.h>

#define NV 4096

typedef __attribute__((ext_vector_type(8))) short bf16x8;
typedef __attribute__((ext_vector_type(4))) float f32x4;

__device__ __forceinline__ unsigned short f2bf(float f) {
  union { float f; unsigned int u; } v; v.f = f;
  unsigned int r = v.u + 0x7FFF + ((v.u >> 16) & 1);  // RNE
  return (unsigned short)(r >> 16);
}

// fused prep: blocks 0..1023 convert feature_map f32->bf16 (8 elems/thread);
// blocks 1024..1295 permute weights (64 x 1088, f=c*17+k) -> Wb[k][o][c] bf16.
__global__ __launch_bounds__(256)
void prep(const float* __restrict__ fm, const float* __restrict__ w,
          unsigned short* __restrict__ fmb, unsigned short* __restrict__ wb) {
  int blk = blockIdx.x;
  if (blk < 1024) {
    int i = (blk * 256 + threadIdx.x) * 8;
    float4 v0 = *(const float4*)(fm + i);
    float4 v1 = *(const float4*)(fm + i + 4);
    ushort4 o0, o1;
    o0.x = f2bf(v0.x); o0.y = f2bf(v0.y); o0.z = f2bf(v0.z); o0.w = f2bf(v0.w);
    o1.x = f2bf(v1.x); o1.y = f2bf(v1.y); o1.z = f2bf(v1.z); o1.w = f2bf(v1.w);
    *(ushort4*)(fmb + i) = o0;
    *(ushort4*)(fmb + i + 4) = o1;
  } else {
    int t = (blk - 1024) * 256 + threadIdx.x;  // 0..69631 (= 17*64*64)
    int c = t & 63;
    int o = (t >> 6) & 63;
    int k = t >> 12;
    wb[t] = f2bf(w[o * 1088 + c * 17 + k]);
  }
}

// BARRIER-FREE gather-GEMM:
//  - W slots 0..15 LDS-resident (131KB, staged once, ONE barrier); slot-16 W
//    fragment in 16 VGPRs.
//  - F slot buffers WAVE-PRIVATE (32 rows x own 32-ch half = 2KB/slot, 3-deep),
//    staged via per-lane-source global_load_lds, synced only by the wave's own
//    vmcnt -> zero barriers in the 17-slot main loop; waves free-run.
//  - Buffer reuse hazard fenced by lgkmcnt(0)+sched_barrier before re-stage.
//  - F granule swizzle g^((row>>1)&3): ds_read 2-way max (free).
// Block = 256 thr = 4 waves (2 row-groups x 2 ch-halves), 64 rows; grid 512.
__global__ __launch_bounds__(256, 1)
void conv_main(const int* __restrict__ nbr, const unsigned short* __restrict__ fmb,
               const unsigned short* __restrict__ wb, const float* __restrict__ bias,
               float* __restrict__ out) {
  extern __shared__ unsigned char smem[];  // 131072 W + 24576 F = 155648

  const int bid = blockIdx.x;
  const int b = bid & 7;               // batch == XCD (512%8==0, bijective)
  const int tile = bid >> 3;           // 0..63
  const int tid = threadIdx.x;
  const int lane = tid & 63;
  const int lm = lane & 15;
  const int lk = lane >> 4;
  const int w4 = tid >> 6;             // wave 0..3
  const int rg = w4 >> 1;              // row-group 0..1 (32 rows)
  const int h = w4 & 1;                // channel half

  const int rbase = tile * 64;
  const bf16x8* fb8 = (const bf16x8*)(fmb + (size_t)b * NV * 64);

  // staging identity: 4 consecutive lanes cover one row's 64B half; lane's
  // two staged rows are (lane>>2) and 16+(lane>>2) of the wave's 32.
  const int grA = rbase + rg * 32 + (lane >> 2);
  const int grB = grA + 16;
  const int gsrc = h * 4 + ((lane & 3) ^ ((lane >> 3) & 3));  // swizzled src granule

  // neighbor indices for the two staged rows
  const int4* qA = (const int4*)(nbr + ((size_t)b * NV + grA) * 16);
  const int4* qB = (const int4*)(nbr + ((size_t)b * NV + grB) * 16);
  const int4 iAa = qA[0], iAb = qA[1], iAc = qA[2], iAd = qA[3];
  const int4 iBa = qB[0], iBb = qB[1], iBc = qB[2], iBd = qB[3];

  // slot-16 W fragment in registers (coalesced 16B loads)
  const int fsl = h * 4 + lk;
  const bf16x8* w16p = (const bf16x8*)(wb + 16 * 4096);
  const bf16x8 X0 = w16p[(0 * 16 + lm) * 8 + fsl];
  const bf16x8 X1 = w16p[(1 * 16 + lm) * 8 + fsl];
  const bf16x8 X2 = w16p[(2 * 16 + lm) * 8 + fsl];
  const bf16x8 X3 = w16p[(3 * 16 + lm) * 8 + fsl];

#define SBR __builtin_amdgcn_sched_barrier(0)
#define MFMA __builtin_amdgcn_mfma_f32_16x16x32_bf16

  // stage W slots 0..15 into LDS (pre-swizzled source, R11-verified pattern)
  #pragma unroll
  for (int i = 0; i < 32; ++i) {
    int t = i * 256 + tid;             // 0..8191
    int o = (t >> 3) & 63;
    int s8 = t & 7;
    int seg = s8 ^ (o & 7);
    const unsigned short* src = wb + (size_t)(t >> 9) * 4096 + o * 64 + seg * 8;
    __builtin_amdgcn_global_load_lds(
        (const __attribute__((address_space(1))) void*)src,
        (__attribute__((address_space(3))) void*)(smem + (size_t)t * 16), 16, 0, 0);
  }
  SBR;

  unsigned char* fbase = smem + 131072 + w4 * 6144;  // wave-private 3 x 2KB

#define STAGE_F(SA, SB, C) {                                                 \
    const bf16x8* sa_ = fb8 + (size_t)(SA) * 8 + gsrc;                       \
    __builtin_amdgcn_global_load_lds(                                        \
        (const __attribute__((address_space(1))) void*)sa_,                  \
        (__attribute__((address_space(3))) void*)(fbase + (C) * 2048 + lane * 16), \
        16, 0, 0);                                                           \
    const bf16x8* sb_ = fb8 + (size_t)(SB) * 8 + gsrc;                       \
    __builtin_amdgcn_global_load_lds(                                        \
        (const __attribute__((address_space(1))) void*)sb_,                  \
        (__attribute__((address_space(3))) void*)(fbase + (C) * 2048 + 1024 + lane * 16), \
        16, 0, 0);                                                           \
  }

  // prologue F stages: slots 0 (self), 1, 2
  STAGE_F(grA, grB, 0); SBR;
  STAGE_F(iAa.x, iBa.x, 1); SBR;
  STAGE_F(iAa.y, iBa.y, 2); SBR;
  asm volatile("s_waitcnt vmcnt(6)" ::: "memory"); SBR;  // all W staged
  __syncthreads();                                        // the ONLY barrier

  // consumer read offsets
  const int offA0 = lm * 64 + ((lk ^ ((lm >> 1) & 3)) << 4);
  const int offW = lm * 128 + ((fsl ^ (lm & 7)) << 4);

  f32x4 accA0{0,0,0,0}, accA1{0,0,0,0}, accA2{0,0,0,0}, accA3{0,0,0,0};
  f32x4 accB0{0,0,0,0}, accB1{0,0,0,0}, accB2{0,0,0,0}, accB3{0,0,0,0};

#define MFMAS(W0_, W1_, W2_, W3_)                                  \
    accA0 = MFMA(A0, W0_, accA0, 0, 0, 0);                         \
    accA1 = MFMA(A0, W1_, accA1, 0, 0, 0);                         \
    accA2 = MFMA(A0, W2_, accA2, 0, 0, 0);                         \
    accA3 = MFMA(A0, W3_, accA3, 0, 0, 0);                         \
    accB0 = MFMA(A1, W0_, accB0, 0, 0, 0);                         \
    accB1 = MFMA(A1, W1_, accB1, 0, 0, 0);                         \
    accB2 = MFMA(A1, W2_, accB2, 0, 0, 0);                         \
    accB3 = MFMA(A1, W3_, accB3, 0, 0, 0);

  // step k: per-wave vmcnt (F(k) ready), 6 ds_read, lgkm-fence, restage buf,
  // 8 MFMA.  NO barriers.
#define STEP(K, CNT, SAN, SBN)                                               \
  asm volatile("s_waitcnt vmcnt(" #CNT ")" ::: "memory"); SBR;               \
  {                                                                          \
    const unsigned char* fp_ = fbase + ((K) % 3) * 2048;                     \
    bf16x8 A0 = *(const bf16x8*)(fp_ + offA0);                               \
    bf16x8 A1 = *(const bf16x8*)(fp_ + 1024 + offA0);                        \
    const unsigned char* wp_ = smem + (K) * 8192;                            \
    bf16x8 W0 = *(const bf16x8*)(wp_ + offW);                                \
    bf16x8 W1 = *(const bf16x8*)(wp_ + 2048 + offW);                         \
    bf16x8 W2 = *(const bf16x8*)(wp_ + 4096 + offW);                         \
    bf16x8 W3 = *(const bf16x8*)(wp_ + 6144 + offW);                         \
    asm volatile("s_waitcnt lgkmcnt(0)" ::: "memory"); SBR;                  \
    STAGE_F(SAN, SBN, (K) % 3); SBR;                                         \
    MFMAS(W0, W1, W2, W3)                                                    \
  }

#define STEPN(K, CNT)                                                        \
  asm volatile("s_waitcnt vmcnt(" #CNT ")" ::: "memory"); SBR;               \
  {                                                                          \
    const unsigned char* fp_ = fbase + ((K) % 3) * 2048;                     \
    bf16x8 A0 = *(const bf16x8*)(fp_ + offA0);                               \
    bf16x8 A1 = *(const bf16x8*)(fp_ + 1024 + offA0);                        \
    const unsigned char* wp_ = smem + (K) * 8192;                            \
    bf16x8 W0 = *(const bf16x8*)(wp_ + offW);                                \
    bf16x8 W1 = *(const bf16x8*)(wp_ + 2048 + offW);                         \
    bf16x8 W2 = *(const bf16x8*)(wp_ + 4096 + offW);                         \
    bf16x8 W3 = *(const bf16x8*)(wp_ + 6144 + offW);                         \
    MFMAS(W0, W1, W2, W3)                                                    \
  }

  STEP(0, 4, iAa.z, iBa.z)
  STEP(1, 4, iAa.w, iBa.w)
  STEP(2, 4, iAb.x, iBb.x)
  STEP(3, 4, iAb.y, iBb.y)
  STEP(4, 4, iAb.z, iBb.z)
  STEP(5, 4, iAb.w, iBb.w)
  STEP(6, 4, iAc.x, iBc.x)
  STEP(7, 4, iAc.y, iBc.y)
  STEP(8, 4, iAc.z, iBc.z)
  STEP(9, 4, iAc.w, iBc.w)
  STEP(10, 4, iAd.x, iBd.x)
  STEP(11, 4, iAd.y, iBd.y)
  STEP(12, 4, iAd.z, iBd.z)
  STEP(13, 4, iAd.w, iBd.w)
  STEPN(14, 4)
  STEPN(15, 2)
  // step 16: W from registers X0..X3, F buf 16%3=1
  asm volatile("s_waitcnt vmcnt(0)" ::: "memory"); SBR;
  {
    const unsigned char* fp_ = fbase + 1 * 2048;
    bf16x8 A0 = *(const bf16x8*)(fp_ + offA0);
    bf16x8 A1 = *(const bf16x8*)(fp_ + 1024 + offA0);
    MFMAS(X0, X1, X2, X3)
  }

#undef STEPN
#undef STEP
#undef MFMAS
#undef STAGE_F
#undef MFMA
#undef SBR

  // reduce h-pairs through LDS (W region dead), epilogue by h==0 waves
  __syncthreads();
  if (h == 1) {
    float* rp = (float*)smem + rg * 2048 + lane * 4;
    *(f32x4*)(rp + 0 * 256) = accA0;
    *(f32x4*)(rp + 1 * 256) = accA1;
    *(f32x4*)(rp + 2 * 256) = accA2;
    *(f32x4*)(rp + 3 * 256) = accA3;
    *(f32x4*)(rp + 4 * 256) = accB0;
    *(f32x4*)(rp + 5 * 256) = accB1;
    *(f32x4*)(rp + 6 * 256) = accB2;
    *(f32x4*)(rp + 7 * 256) = accB3;
  }
  __syncthreads();
  if (h == 0) {
    const float* rp = (const float*)smem + rg * 2048 + lane * 4;
    accA0 += *(const f32x4*)(rp + 0 * 256);
    accA1 += *(const f32x4*)(rp + 1 * 256);
    accA2 += *(const f32x4*)(rp + 2 * 256);
    accA3 += *(const f32x4*)(rp + 3 * 256);
    accB0 += *(const f32x4*)(rp + 4 * 256);
    accB1 += *(const f32x4*)(rp + 5 * 256);
    accB2 += *(const f32x4*)(rp + 6 * 256);
    accB3 += *(const f32x4*)(rp + 7 * 256);

    const float bv0 = bias[lm];
    const float bv1 = bias[16 + lm];
    const float bv2 = bias[32 + lm];
    const float bv3 = bias[48 + lm];
    float* op = out + (size_t)b * NV * 64;
    #pragma unroll
    for (int mt = 0; mt < 2; ++mt) {
      const int gv = rbase + rg * 32 + mt * 16 + lk * 4;
      #pragma unroll
      for (int r = 0; r < 4; ++r) {
        float* orow = op + (size_t)(gv + r) * 64;
        if (mt == 0) {
          orow[lm]      = fmaxf(accA0[r] + bv0, 0.f);
          orow[16 + lm] = fmaxf(accA1[r] + bv1, 0.f);
          orow[32 + lm] = fmaxf(accA2[r] + bv2, 0.f);
          orow[48 + lm] = fmaxf(accA3[r] + bv3, 0.f);
        } else {
          orow[lm]      = fmaxf(accB0[r] + bv0, 0.f);
          orow[16 + lm] = fmaxf(accB1[r] + bv1, 0.f);
          orow[32 + lm] = fmaxf(accB2[r] + bv2, 0.f);
          orow[48 + lm] = fmaxf(accB3[r] + bv3, 0.f);
        }
      }
    }
  }
}

extern "C" void kernel_launch(void* const* d_in, const int* in_sizes, int n_in,
                              void* d_out, int out_size, void* d_ws, size_t ws_size,
                              hipStream_t stream) {
  const int* nbr = (const int*)d_in[0];
  // d_in[1] = vertices (unused by the reference computation)
  const float* fm = (const float*)d_in[2];
  const float* w = (const float*)d_in[3];
  const float* bias = (const float*)d_in[4];
  float* out = (float*)d_out;

  unsigned short* fmb = (unsigned short*)d_ws;          // 8*4096*64 bf16 = 4 MB
  unsigned short* wb = fmb + (size_t)8 * NV * 64;       // 17*64*64 bf16

  hipFuncSetAttribute((const void*)conv_main,
                      hipFuncAttributeMaxDynamicSharedMemorySize, 155648);

  prep<<<1296, 256, 0, stream>>>(fm, w, fmb, wb);
  conv_main<<<512, 256, 155648, stream>>>(nbr, fmb, wb, bias, out);
}

// Round 14
// 21.991 us; speedup vs baseline: 1.0463x; 1.0463x over previous
//
#include <hip/hip_runtime.h>
#include <hip/hip_bf16.h>
#include <stdint.h>

#define NV 4096

typedef __attribute__((ext_vector_type(8))) short bf16x8;
typedef __attribute__((ext_vector_type(4))) float f32x4;

__device__ __forceinline__ unsigned short f2bf(float f) {
  union { float f; unsigned int u; } v; v.f = f;
  unsigned int r = v.u + 0x7FFF + ((v.u >> 16) & 1);  // RNE
  return (unsigned short)(r >> 16);
}

// prep: WEIGHTS ONLY (fm conversion fused into conv).
// permute weights (64 x 1088, f = c*17+k) -> Wb[k][o][c] bf16.
__global__ __launch_bounds__(256)
void prep_w(const float* __restrict__ w, unsigned short* __restrict__ wb) {
  int t = blockIdx.x * 256 + threadIdx.x;  // 0..69631 (= 17*64*64)
  int c = t & 63;
  int o = (t >> 6) & 63;
  int k = t >> 12;
  wb[t] = f2bf(w[o * 1088 + c * 17 + k]);
}

__device__ __forceinline__ bf16x8 cvt8(f32x4 lo, f32x4 hi) {
  union { bf16x8 v; __hip_bfloat162 h[4]; } u;
  u.h[0] = __float22bfloat162_rn(make_float2(lo[0], lo[1]));
  u.h[1] = __float22bfloat162_rn(make_float2(lo[2], lo[3]));
  u.h[2] = __float22bfloat162_rn(make_float2(hi[0], hi[1]));
  u.h[3] = __float22bfloat162_rn(make_float2(hi[2], hi[3]));
  return u.v;
}

// R11 structure, but F gathered as f32 DIRECTLY from feature_map (no fm-prep):
//  - cooperative gload_lds: 16-lane groups fetch one 256B f32 row contiguously;
//    source granule pre-swizzled (g ^ ((row&7)<<1), involution) so consumer
//    ds_reads are 2-way max;
//  - f32->bf16 conversion on consume via v_cvt_pk (RNE, matches old prep);
//  - neighbor indices in a 4KB LDS tile (staged once in prologue);
//  - W staged per-slot from wb exactly as R11; triple-buffered rounds,
//    counted vmcnt(6) + raw barrier per round.
// Block = 256 thr = 4 waves (2 row-groups x 2 ch-halves), 64 rows; grid 512.
__global__ __launch_bounds__(256, 2)
void conv_main(const int* __restrict__ nbr, const float* __restrict__ fm,
               const unsigned short* __restrict__ wb, const float* __restrict__ bias,
               float* __restrict__ out) {
  __shared__ unsigned char smem[77824];  // W 3x8K @0, F 3x16K @24576, idx 4K @73728

  const int bid = blockIdx.x;
  const int b = bid & 7;               // batch == XCD (512%8==0, bijective)
  const int tile = bid >> 3;           // 0..63
  const int tid = threadIdx.x;
  const int lane = tid & 63;
  const int lm = lane & 15;
  const int lk = lane >> 4;
  const int w4 = tid >> 6;             // wave 0..3
  const int rg = w4 >> 1;              // row-group 0..1 (32 rows)
  const int h = w4 & 1;                // channel half

  const int rbase = tile * 64;
  const float* fb32 = fm + (size_t)b * NV * 64;

  // consumer read offsets
  const int fsl = h * 4 + lk;          // 16B(bf16)/8ch segment id, 0..7
  const int offW = lm * 128 + ((fsl ^ (lm & 7)) << 4);
  const int offF0 = (rg * 32 + lm) * 256 + (((2 * fsl) ^ ((lm & 7) << 1)) << 4);

  f32x4 accA0{0,0,0,0}, accA1{0,0,0,0}, accA2{0,0,0,0}, accA3{0,0,0,0};
  f32x4 accB0{0,0,0,0}, accB1{0,0,0,0}, accB2{0,0,0,0}, accB3{0,0,0,0};

#define SBR __builtin_amdgcn_sched_barrier(0)
#define MFMA __builtin_amdgcn_mfma_f32_16x16x32_bf16

  // stage slot K: W (2 gloads, R11-verified) + F rows as f32 (4 gloads,
  // 16-lane-contiguous source, granule-swizzled).
#define STAGE(K, C) {                                                       \
    _Pragma("unroll")                                                       \
    for (int i_ = 0; i_ < 2; ++i_) {                                        \
      int t_ = i_ * 256 + tid;                                              \
      int o_ = (t_ >> 3) & 63, s_ = t_ & 7;                                 \
      const unsigned short* ws_ =                                           \
          wb + (K) * 4096 + o_ * 64 + ((s_ ^ (o_ & 7)) << 3);               \
      __builtin_amdgcn_global_load_lds(                                     \
          (const __attribute__((address_space(1))) void*)ws_,               \
          (__attribute__((address_space(3))) void*)(smem + (C) * 8192 + t_ * 16), \
          16, 0, 0);                                                        \
    }                                                                       \
    _Pragma("unroll")                                                       \
    for (int i_ = 0; i_ < 4; ++i_) {                                        \
      int row_ = w4 * 16 + i_ * 4 + (lane >> 4);                            \
      int sv_;                                                              \
      if ((K) == 0) sv_ = rbase + row_;                                     \
      else sv_ = *(const int*)(smem + 73728 + row_ * 64 + ((K) - 1) * 4);   \
      int gs_ = (lane & 15) ^ ((row_ & 7) << 1);                            \
      const float* fs_ = fb32 + (size_t)sv_ * 64 + gs_ * 4;                 \
      __builtin_amdgcn_global_load_lds(                                     \
          (const __attribute__((address_space(1))) void*)fs_,               \
          (__attribute__((address_space(3))) void*)(smem + 24576 + (C) * 16384 \
              + (size_t)row_ * 256 + (lane & 15) * 16),                     \
          16, 0, 0);                                                        \
    }                                                                       \
  }

#define CONSUME(K, C) {                                                    \
    const unsigned char* wp_ = smem + (C) * 8192;                          \
    const unsigned char* fp_ = smem + 24576 + (C) * 16384;                 \
    bf16x8 W0 = *(const bf16x8*)(wp_ + 0 * 2048 + offW);                   \
    bf16x8 W1 = *(const bf16x8*)(wp_ + 1 * 2048 + offW);                   \
    bf16x8 W2 = *(const bf16x8*)(wp_ + 2 * 2048 + offW);                   \
    bf16x8 W3 = *(const bf16x8*)(wp_ + 3 * 2048 + offW);                   \
    f32x4 lo0 = *(const f32x4*)(fp_ + offF0);                              \
    f32x4 hi0 = *(const f32x4*)(fp_ + offF0 + 16);                         \
    f32x4 lo1 = *(const f32x4*)(fp_ + offF0 + 4096);                       \
    f32x4 hi1 = *(const f32x4*)(fp_ + offF0 + 4096 + 16);                  \
    bf16x8 A0 = cvt8(lo0, hi0);                                            \
    bf16x8 A1 = cvt8(lo1, hi1);                                            \
    accA0 = MFMA(A0, W0, accA0, 0, 0, 0);                                  \
    accA1 = MFMA(A0, W1, accA1, 0, 0, 0);                                  \
    accA2 = MFMA(A0, W2, accA2, 0, 0, 0);                                  \
    accA3 = MFMA(A0, W3, accA3, 0, 0, 0);                                  \
    accB0 = MFMA(A1, W0, accB0, 0, 0, 0);                                  \
    accB1 = MFMA(A1, W1, accB1, 0, 0, 0);                                  \
    accB2 = MFMA(A1, W2, accB2, 0, 0, 0);                                  \
    accB3 = MFMA(A1, W3, accB3, 0, 0, 0);                                  \
  }

#define WAITBAR(N)                                                          \
    SBR; asm volatile("s_waitcnt vmcnt(" #N ")" ::: "memory"); SBR;         \
    __builtin_amdgcn_s_barrier(); SBR;

  // prologue: idx int4 load + slot-0 stage overlap; one full drain; slot 1.
  const int4 myidx = ((const int4*)(nbr + ((size_t)b * NV + rbase) * 16))[tid];
  STAGE(0, 0); SBR;
  ((int4*)(smem + 73728))[tid] = myidx;   // compiler waits idx only (counted)
  __syncthreads();                        // idx tile + slot 0 complete
  STAGE(1, 1); SBR;

  // steady state: stage slot k+2 into buf (k+2)%3, consume buf k%3,
  // vmcnt(6) drains slot k+1 (slot k+2's 6 loads stay in flight), barrier.
  STAGE(2, 2);  SBR; CONSUME(0, 0);  WAITBAR(6);
  STAGE(3, 0);  SBR; CONSUME(1, 1);  WAITBAR(6);
  STAGE(4, 1);  SBR; CONSUME(2, 2);  WAITBAR(6);
  STAGE(5, 2);  SBR; CONSUME(3, 0);  WAITBAR(6);
  STAGE(6, 0);  SBR; CONSUME(4, 1);  WAITBAR(6);
  STAGE(7, 1);  SBR; CONSUME(5, 2);  WAITBAR(6);
  STAGE(8, 2);  SBR; CONSUME(6, 0);  WAITBAR(6);
  STAGE(9, 0);  SBR; CONSUME(7, 1);  WAITBAR(6);
  STAGE(10, 1); SBR; CONSUME(8, 2);  WAITBAR(6);
  STAGE(11, 2); SBR; CONSUME(9, 0);  WAITBAR(6);
  STAGE(12, 0); SBR; CONSUME(10, 1); WAITBAR(6);
  STAGE(13, 1); SBR; CONSUME(11, 2); WAITBAR(6);
  STAGE(14, 2); SBR; CONSUME(12, 0); WAITBAR(6);
  STAGE(15, 0); SBR; CONSUME(13, 1); WAITBAR(6);
  STAGE(16, 1); SBR; CONSUME(14, 2); WAITBAR(6);
  CONSUME(15, 0); WAITBAR(0);
  CONSUME(16, 1);

#undef WAITBAR
#undef CONSUME
#undef STAGE
#undef MFMA
#undef SBR

  // reduce h-pairs through LDS (W region dead), epilogue by h==0 waves
  __syncthreads();
  if (h == 1) {
    float* rp = (float*)smem + rg * 2048 + lane * 4;
    *(f32x4*)(rp + 0 * 256) = accA0;
    *(f32x4*)(rp + 1 * 256) = accA1;
    *(f32x4*)(rp + 2 * 256) = accA2;
    *(f32x4*)(rp + 3 * 256) = accA3;
    *(f32x4*)(rp + 4 * 256) = accB0;
    *(f32x4*)(rp + 5 * 256) = accB1;
    *(f32x4*)(rp + 6 * 256) = accB2;
    *(f32x4*)(rp + 7 * 256) = accB3;
  }
  __syncthreads();
  if (h == 0) {
    const float* rp = (const float*)smem + rg * 2048 + lane * 4;
    accA0 += *(const f32x4*)(rp + 0 * 256);
    accA1 += *(const f32x4*)(rp + 1 * 256);
    accA2 += *(const f32x4*)(rp + 2 * 256);
    accA3 += *(const f32x4*)(rp + 3 * 256);
    accB0 += *(const f32x4*)(rp + 4 * 256);
    accB1 += *(const f32x4*)(rp + 5 * 256);
    accB2 += *(const f32x4*)(rp + 6 * 256);
    accB3 += *(const f32x4*)(rp + 7 * 256);

    const float bv0 = bias[lm];
    const float bv1 = bias[16 + lm];
    const float bv2 = bias[32 + lm];
    const float bv3 = bias[48 + lm];
    float* op = out + (size_t)b * NV * 64;
    #pragma unroll
    for (int mt = 0; mt < 2; ++mt) {
      const int gv = rbase + rg * 32 + mt * 16 + lk * 4;
      #pragma unroll
      for (int r = 0; r < 4; ++r) {
        float* orow = op + (size_t)(gv + r) * 64;
        if (mt == 0) {
          orow[lm]      = fmaxf(accA0[r] + bv0, 0.f);
          orow[16 + lm] = fmaxf(accA1[r] + bv1, 0.f);
          orow[32 + lm] = fmaxf(accA2[r] + bv2, 0.f);
          orow[48 + lm] = fmaxf(accA3[r] + bv3, 0.f);
        } else {
          orow[lm]      = fmaxf(accB0[r] + bv0, 0.f);
          orow[16 + lm] = fmaxf(accB1[r] + bv1, 0.f);
          orow[32 + lm] = fmaxf(accB2[r] + bv2, 0.f);
          orow[48 + lm] = fmaxf(accB3[r] + bv3, 0.f);
        }
      }
    }
  }
}

extern "C" void kernel_launch(void* const* d_in, const int* in_sizes, int n_in,
                              void* d_out, int out_size, void* d_ws, size_t ws_size,
                              hipStream_t stream) {
  const int* nbr = (const int*)d_in[0];
  // d_in[1] = vertices (unused by the reference computation)
  const float* fm = (const float*)d_in[2];
  const float* w = (const float*)d_in[3];
  const float* bias = (const float*)d_in[4];
  float* out = (float*)d_out;

  unsigned short* wb = (unsigned short*)d_ws;           // 17*64*64 bf16

  prep_w<<<272, 256, 0, stream>>>(w, wb);
  conv_main<<<512, 256, 0, stream>>>(nbr, fm, wb, bias, out);
}

// Round 15
// 20.639 us; speedup vs baseline: 1.1148x; 1.0655x over previous
//
#include <hip/hip_runtime.h>
#include <stdint.h>

#define NV 4096

typedef __attribute__((ext_vector_type(8))) short bf16x8;
typedef __attribute__((ext_vector_type(4))) float f32x4;

__device__ __forceinline__ unsigned short f2bf(float f) {
  union { float f; unsigned int u; } v; v.f = f;
  unsigned int r = v.u + 0x7FFF + ((v.u >> 16) & 1);  // RNE
  return (unsigned short)(r >> 16);
}

// fused prep: blocks 0..1023 convert feature_map f32->bf16 (8 elems/thread);
// blocks 1024..1295 permute weights (64 x 1088, f=c*17+k) -> Wb[k][o][c] bf16.
__global__ __launch_bounds__(256)
void prep(const float* __restrict__ fm, const float* __restrict__ w,
          unsigned short* __restrict__ fmb, unsigned short* __restrict__ wb) {
  int blk = blockIdx.x;
  if (blk < 1024) {
    int i = (blk * 256 + threadIdx.x) * 8;
    float4 v0 = *(const float4*)(fm + i);
    float4 v1 = *(const float4*)(fm + i + 4);
    ushort4 o0, o1;
    o0.x = f2bf(v0.x); o0.y = f2bf(v0.y); o0.z = f2bf(v0.z); o0.w = f2bf(v0.w);
    o1.x = f2bf(v1.x); o1.y = f2bf(v1.y); o1.z = f2bf(v1.z); o1.w = f2bf(v1.w);
    *(ushort4*)(fmb + i) = o0;
    *(ushort4*)(fmb + i + 4) = o1;
  } else {
    int t = (blk - 1024) * 256 + threadIdx.x;  // 0..69631 (= 17*64*64)
    int c = t & 63;
    int o = (t >> 6) & 63;
    int k = t >> 12;
    wb[t] = f2bf(w[o * 1088 + c * 17 + k]);
  }
}

// R11 cooperative LDS-gather GEMM + PARITY RETILE of consumers:
//  staging/buffers/vmcnt/barriers identical to verified R11.  Wave (p,h)
//  consumes only slots with k&1==p, covering all 4 row-tiles x 4 col-tiles
//  of channel-half h: 16 MFMAs per 8 ds_read_b128 (was 8 per 6) -> block
//  LDS reads per slot 24 -> 16.  s_setprio(1) around the 16-MFMA cluster.
//  Epilogue: distributed 4-way (p,h) reduction through LDS in 2 rounds.
// Block = 256 thr = 4 waves, 64 rows; grid 512 (2 blocks/CU).
__global__ __launch_bounds__(256, 2)
void conv_main(const int* __restrict__ nbr, const unsigned short* __restrict__ fmb,
               const unsigned short* __restrict__ wb, const float* __restrict__ bias,
               float* __restrict__ out) {
  __shared__ unsigned char smem[49152];  // W: 3x8KB @0, F: 3x8KB @24576

  const int bid = blockIdx.x;
  const int b = bid & 7;               // batch == XCD (512%8==0, bijective)
  const int tile = bid >> 3;           // 0..63
  const int tid = threadIdx.x;
  const int lane = tid & 63;
  const int lm = lane & 15;
  const int lk = lane >> 4;
  const int w4 = tid >> 6;             // wave 0..3
  const int p = w4 & 1;                // slot parity this wave consumes
  const int h = w4 >> 1;               // channel half

  const int rbase = tile * 64;
  const bf16x8* fb8 = (const bf16x8*)(fmb + (size_t)b * NV * 64);

  // staging identity (unchanged from R11): thread t stages F granules for
  // rows (t>>3) and 32+(t>>3); 8 consecutive lanes cover one row's 128B.
  const int r0 = tid >> 3;
  const int c8 = tid & 7;
  const int swz = c8 ^ (r0 & 7);
  const int row0g = rbase + r0;
  const int row1g = rbase + r0 + 32;

  const int4* q0 = (const int4*)(nbr + ((size_t)b * NV + row0g) * 16);
  const int4* q1 = (const int4*)(nbr + ((size_t)b * NV + row1g) * 16);
  const int4 i0a = q0[0], i0b = q0[1], i0c = q0[2], i0d = q0[3];
  const int4 i1a = q1[0], i1b = q1[1], i1c = q1[2], i1d = q1[3];

  // consumer read offsets: W row o and F row r share the same [64][8-seg]
  // swizzled layout; (x*16+lm)&7 == lm&7 so one base + tile*2048 strides.
  const int fsl = h * 4 + lk;
  const int offB = lm * 128 + ((fsl ^ (lm & 7)) << 4);

  f32x4 acc00{0,0,0,0}, acc01{0,0,0,0}, acc02{0,0,0,0}, acc03{0,0,0,0};
  f32x4 acc10{0,0,0,0}, acc11{0,0,0,0}, acc12{0,0,0,0}, acc13{0,0,0,0};
  f32x4 acc20{0,0,0,0}, acc21{0,0,0,0}, acc22{0,0,0,0}, acc23{0,0,0,0};
  f32x4 acc30{0,0,0,0}, acc31{0,0,0,0}, acc32{0,0,0,0}, acc33{0,0,0,0};

#define SBR __builtin_amdgcn_sched_barrier(0)
#define MFMA __builtin_amdgcn_mfma_f32_16x16x32_bf16

#define STAGE(SLOT, BUF) {                                                  \
    _Pragma("unroll")                                                       \
    for (int i_ = 0; i_ < 2; ++i_) {                                        \
      int t_ = i_ * 256 + tid;                                              \
      int o_ = (t_ >> 3) & 63, s_ = t_ & 7;                                 \
      const unsigned short* ws_ =                                           \
          wb + (SLOT) * 4096 + o_ * 64 + ((s_ ^ (o_ & 7)) << 3);            \
      __builtin_amdgcn_global_load_lds(                                     \
          (const __attribute__((address_space(1))) void*)ws_,               \
          (__attribute__((address_space(3))) void*)(smem + (BUF) * 8192 + t_ * 16), \
          16, 0, 0);                                                        \
    }                                                                       \
    {                                                                       \
      const bf16x8* fa_ = fb8 + (size_t)(SVA_) * 8 + swz;                   \
      __builtin_amdgcn_global_load_lds(                                     \
          (const __attribute__((address_space(1))) void*)fa_,               \
          (__attribute__((address_space(3))) void*)(smem + 24576 + (BUF) * 8192 + tid * 16), \
          16, 0, 0);                                                        \
      const bf16x8* fbp_ = fb8 + (size_t)(SVB_) * 8 + swz;                  \
      __builtin_amdgcn_global_load_lds(                                     \
          (const __attribute__((address_space(1))) void*)fbp_,              \
          (__attribute__((address_space(3))) void*)(smem + 24576 + (BUF) * 8192 + 4096 + tid * 16), \
          16, 0, 0);                                                        \
    }                                                                       \
  }
#define STAGES(SLOT, BUF, SA, SB) { const int SVA_ = (SA), SVB_ = (SB); STAGE(SLOT, BUF) }

#define CONSUME(BUF) {                                                     \
    const unsigned char* wp_ = smem + (BUF) * 8192;                        \
    const unsigned char* fp_ = smem + 24576 + (BUF) * 8192;                \
    bf16x8 W0 = *(const bf16x8*)(wp_ + offB);                              \
    bf16x8 W1 = *(const bf16x8*)(wp_ + 2048 + offB);                       \
    bf16x8 W2 = *(const bf16x8*)(wp_ + 4096 + offB);                       \
    bf16x8 W3 = *(const bf16x8*)(wp_ + 6144 + offB);                       \
    bf16x8 A0 = *(const bf16x8*)(fp_ + offB);                              \
    bf16x8 A1 = *(const bf16x8*)(fp_ + 2048 + offB);                       \
    bf16x8 A2 = *(const bf16x8*)(fp_ + 4096 + offB);                       \
    bf16x8 A3 = *(const bf16x8*)(fp_ + 6144 + offB);                       \
    __builtin_amdgcn_s_setprio(1);                                         \
    acc00 = MFMA(A0, W0, acc00, 0, 0, 0);                                  \
    acc01 = MFMA(A0, W1, acc01, 0, 0, 0);                                  \
    acc02 = MFMA(A0, W2, acc02, 0, 0, 0);                                  \
    acc03 = MFMA(A0, W3, acc03, 0, 0, 0);                                  \
    acc10 = MFMA(A1, W0, acc10, 0, 0, 0);                                  \
    acc11 = MFMA(A1, W1, acc11, 0, 0, 0);                                  \
    acc12 = MFMA(A1, W2, acc12, 0, 0, 0);                                  \
    acc13 = MFMA(A1, W3, acc13, 0, 0, 0);                                  \
    acc20 = MFMA(A2, W0, acc20, 0, 0, 0);                                  \
    acc21 = MFMA(A2, W1, acc21, 0, 0, 0);                                  \
    acc22 = MFMA(A2, W2, acc22, 0, 0, 0);                                  \
    acc23 = MFMA(A2, W3, acc23, 0, 0, 0);                                  \
    acc30 = MFMA(A3, W0, acc30, 0, 0, 0);                                  \
    acc31 = MFMA(A3, W1, acc31, 0, 0, 0);                                  \
    acc32 = MFMA(A3, W2, acc32, 0, 0, 0);                                  \
    acc33 = MFMA(A3, W3, acc33, 0, 0, 0);                                  \
    __builtin_amdgcn_s_setprio(0);                                         \
  }

#define WAITBAR(N)                                                          \
    SBR; asm volatile("s_waitcnt vmcnt(" #N ")" ::: "memory"); SBR;         \
    __builtin_amdgcn_s_barrier(); SBR;

  // prologue (R11-identical): stage slots 0,1; drain slot 0
  STAGES(0, 0, row0g, row1g); SBR;
  STAGES(1, 1, i0a.x, i1a.x); SBR;
  WAITBAR(4);

  // round k: stage slot k+2 into buf (k+2)%3; waves with p==k&1 consume
  // buf k%3; vmcnt(4) drains slot k+1's staging; barrier.
  STAGES(2, 2, i0a.y, i1a.y);  SBR; if (p == 0) CONSUME(0); WAITBAR(4);  // k=0
  STAGES(3, 0, i0a.z, i1a.z);  SBR; if (p == 1) CONSUME(1); WAITBAR(4);  // k=1
  STAGES(4, 1, i0a.w, i1a.w);  SBR; if (p == 0) CONSUME(2); WAITBAR(4);  // k=2
  STAGES(5, 2, i0b.x, i1b.x);  SBR; if (p == 1) CONSUME(0); WAITBAR(4);  // k=3
  STAGES(6, 0, i0b.y, i1b.y);  SBR; if (p == 0) CONSUME(1); WAITBAR(4);  // k=4
  STAGES(7, 1, i0b.z, i1b.z);  SBR; if (p == 1) CONSUME(2); WAITBAR(4);  // k=5
  STAGES(8, 2, i0b.w, i1b.w);  SBR; if (p == 0) CONSUME(0); WAITBAR(4);  // k=6
  STAGES(9, 0, i0c.x, i1c.x);  SBR; if (p == 1) CONSUME(1); WAITBAR(4);  // k=7
  STAGES(10, 1, i0c.y, i1c.y); SBR; if (p == 0) CONSUME(2); WAITBAR(4);  // k=8
  STAGES(11, 2, i0c.z, i1c.z); SBR; if (p == 1) CONSUME(0); WAITBAR(4);  // k=9
  STAGES(12, 0, i0c.w, i1c.w); SBR; if (p == 0) CONSUME(1); WAITBAR(4);  // k=10
  STAGES(13, 1, i0d.x, i1d.x); SBR; if (p == 1) CONSUME(2); WAITBAR(4);  // k=11
  STAGES(14, 2, i0d.y, i1d.y); SBR; if (p == 0) CONSUME(0); WAITBAR(4);  // k=12
  STAGES(15, 0, i0d.z, i1d.z); SBR; if (p == 1) CONSUME(1); WAITBAR(4);  // k=13
  STAGES(16, 1, i0d.w, i1d.w); SBR; if (p == 0) CONSUME(2); WAITBAR(4);  // k=14
  if (p == 1) CONSUME(0); WAITBAR(0);                                    // k=15
  if (p == 0) CONSUME(1);                                                // k=16

#undef WAITBAR
#undef CONSUME
#undef STAGES
#undef STAGE
#undef MFMA
#undef SBR

  // distributed 4-way (p,h) reduction + epilogue, 2 rounds of row-tiles.
  // region: [wave][cell 0..7][lane] f32x4 = 32KB in dead buffers.
  float* op = out + (size_t)b * NV * 64;
#define REDROUND(RTB, a0x0, a0x1, a0x2, a0x3, a1x0, a1x1, a1x2, a1x3)       \
  __syncthreads();                                                          \
  {                                                                         \
    unsigned char* wr_ = smem + w4 * 8192 + lane * 16;                      \
    *(f32x4*)(wr_ + 0 * 1024) = a0x0; *(f32x4*)(wr_ + 1 * 1024) = a0x1;     \
    *(f32x4*)(wr_ + 2 * 1024) = a0x2; *(f32x4*)(wr_ + 3 * 1024) = a0x3;     \
    *(f32x4*)(wr_ + 4 * 1024) = a1x0; *(f32x4*)(wr_ + 5 * 1024) = a1x1;     \
    *(f32x4*)(wr_ + 6 * 1024) = a1x2; *(f32x4*)(wr_ + 7 * 1024) = a1x3;     \
  }                                                                         \
  __syncthreads();                                                          \
  _Pragma("unroll")                                                         \
  for (int j_ = 0; j_ < 2; ++j_) {                                          \
    int cell_ = w4 * 2 + j_;                                                \
    const unsigned char* rb_ = smem + cell_ * 1024 + lane * 16;             \
    f32x4 s_ = *(const f32x4*)(rb_);                                        \
    s_ += *(const f32x4*)(rb_ + 8192);                                      \
    s_ += *(const f32x4*)(rb_ + 16384);                                     \
    s_ += *(const f32x4*)(rb_ + 24576);                                     \
    int rt_ = (RTB) + (cell_ >> 2);                                         \
    int n_ = cell_ & 3;                                                     \
    int o_ = n_ * 16 + lm;                                                  \
    float bv_ = bias[o_];                                                   \
    int gv_ = rbase + rt_ * 16 + lk * 4;                                    \
    _Pragma("unroll")                                                       \
    for (int r_ = 0; r_ < 4; ++r_)                                          \
      op[(size_t)(gv_ + r_) * 64 + o_] = fmaxf(s_[r_] + bv_, 0.f);          \
  }

  REDROUND(0, acc00, acc01, acc02, acc03, acc10, acc11, acc12, acc13)
  REDROUND(2, acc20, acc21, acc22, acc23, acc30, acc31, acc32, acc33)
#undef REDROUND
}

extern "C" void kernel_launch(void* const* d_in, const int* in_sizes, int n_in,
                              void* d_out, int out_size, void* d_ws, size_t ws_size,
                              hipStream_t stream) {
  const int* nbr = (const int*)d_in[0];
  // d_in[1] = vertices (unused by the reference computation)
  const float* fm = (const float*)d_in[2];
  const float* w = (const float*)d_in[3];
  const float* bias = (const float*)d_in[4];
  float* out = (float*)d_out;

  unsigned short* fmb = (unsigned short*)d_ws;          // 8*4096*64 bf16 = 4 MB
  unsigned short* wb = fmb + (size_t)8 * NV * 64;       // 17*64*64 bf16

  prep<<<1296, 256, 0, stream>>>(fm, w, fmb, wb);
  conv_main<<<512, 256, 0, stream>>>(nbr, fmb, wb, bias, out);
}

// Round 17
// 19.754 us; speedup vs baseline: 1.1648x; 1.0448x over previous
//
#include <hip/hip_runtime.h>
#include <stdint.h>

#define NV 4096

typedef __attribute__((ext_vector_type(8))) short bf16x8;
typedef __attribute__((ext_vector_type(4))) float f32x4;

__device__ __forceinline__ unsigned short f2bf(float f) {
  union { float f; unsigned int u; } v; v.f = f;
  unsigned int r = v.u + 0x7FFF + ((v.u >> 16) & 1);  // RNE
  return (unsigned short)(r >> 16);
}

// fused prep: blocks 0..1023 convert feature_map f32->bf16 (8 elems/thread);
// blocks 1024..1295 permute weights (64 x 1088, f=c*17+k) -> Wb[k][o][c] bf16.
__global__ __launch_bounds__(256)
void prep(const float* __restrict__ fm, const float* __restrict__ w,
          unsigned short* __restrict__ fmb, unsigned short* __restrict__ wb) {
  int blk = blockIdx.x;
  if (blk < 1024) {
    int i = (blk * 256 + threadIdx.x) * 8;
    float4 v0 = *(const float4*)(fm + i);
    float4 v1 = *(const float4*)(fm + i + 4);
    ushort4 o0, o1;
    o0.x = f2bf(v0.x); o0.y = f2bf(v0.y); o0.z = f2bf(v0.z); o0.w = f2bf(v0.w);
    o1.x = f2bf(v1.x); o1.y = f2bf(v1.y); o1.z = f2bf(v1.z); o1.w = f2bf(v1.w);
    *(ushort4*)(fmb + i) = o0;
    *(ushort4*)(fmb + i + 4) = o1;
  } else {
    int t = (blk - 1024) * 256 + threadIdx.x;  // 0..69631 (= 17*64*64)
    int c = t & 63;
    int o = (t >> 6) & 63;
    int k = t >> 12;
    wb[t] = f2bf(w[o * 1088 + c * 17 + k]);
  }
}

// R11 cooperative LDS-gather GEMM, 128-ROW TILE (halves W duplication):
//  block = 512 thr = 8 waves = 4 row-groups x 2 ch-halves; 128 rows/block;
//  grid 256 (1 block/CU).  Staged bytes/CU: 408KB vs R11's 544KB (-25%).
//  Same staging pattern (8-lane cooperative gload_lds, involution swizzle),
//  triple-buffered slots, counted vmcnt(3) (3 loads/thread/slot) + barrier.
__global__ __launch_bounds__(512, 2)
void conv_main(const int* __restrict__ nbr, const unsigned short* __restrict__ fmb,
               const unsigned short* __restrict__ wb, const float* __restrict__ bias,
               float* __restrict__ out) {
  __shared__ unsigned char smem[73728];  // W: 3x8KB @0, F: 3x16KB @24576

  const int bid = blockIdx.x;
  const int b = bid & 7;               // batch == XCD (256%8==0, bijective)
  const int tile = bid >> 3;           // 0..31
  const int tid = threadIdx.x;         // 0..511
  const int lane = tid & 63;
  const int lm = lane & 15;
  const int lk = lane >> 4;
  const int w8 = tid >> 6;             // wave 0..7
  const int rg = w8 >> 1;              // row-group 0..3 (32 rows)
  const int h = w8 & 1;                // channel half

  const int rbase = tile * 128;
  const bf16x8* fb8 = (const bf16x8*)(fmb + (size_t)b * NV * 64);

  // staging identity: thread t stages F granule (t&7) of rows (t>>3) and
  // (t>>3)+64; 8 consecutive lanes cover one row's 128B contiguously.
  const int r0 = tid >> 3;             // 0..63
  const int c8 = tid & 7;
  const int swz = c8 ^ (r0 & 7);       // source-granule swizzle ((r0+64)&7==r0&7)
  const int row0g = rbase + r0;
  const int row1g = rbase + r0 + 64;

  const int4* q0 = (const int4*)(nbr + ((size_t)b * NV + row0g) * 16);
  const int4* q1 = (const int4*)(nbr + ((size_t)b * NV + row1g) * 16);
  const int4 i0a = q0[0], i0b = q0[1], i0c = q0[2], i0d = q0[3];
  const int4 i1a = q1[0], i1b = q1[1], i1c = q1[2], i1d = q1[3];

  // consumer read offsets (R11-verified math, rg extended to 0..3)
  const int fsl = h * 4 + lk;
  const int offW = lm * 128 + ((fsl ^ (lm & 7)) << 4);
  const int rowL0 = rg * 32 + lm;
  const int rowL1 = rg * 32 + 16 + lm;
  const int offA0 = rowL0 * 128 + ((fsl ^ (rowL0 & 7)) << 4);
  const int offA1 = rowL1 * 128 + ((fsl ^ (rowL1 & 7)) << 4);

  f32x4 accA0{0,0,0,0}, accA1{0,0,0,0}, accA2{0,0,0,0}, accA3{0,0,0,0};
  f32x4 accB0{0,0,0,0}, accB1{0,0,0,0}, accB2{0,0,0,0}, accB3{0,0,0,0};

#define SBR __builtin_amdgcn_sched_barrier(0)
#define MFMA __builtin_amdgcn_mfma_f32_16x16x32_bf16

  // 3 gloads/thread: 1 W granule + 2 F rows (sources pre-swizzled)
#define STAGE(SLOT, BUF, SVA, SVB) {                                        \
    {                                                                       \
      int o_ = (tid >> 3) & 63, s_ = tid & 7;                               \
      const unsigned short* ws_ =                                           \
          wb + (SLOT) * 4096 + o_ * 64 + ((s_ ^ (o_ & 7)) << 3);            \
      __builtin_amdgcn_global_load_lds(                                     \
          (const __attribute__((address_space(1))) void*)ws_,               \
          (__attribute__((address_space(3))) void*)(smem + (BUF) * 8192 + tid * 16), \
          16, 0, 0);                                                        \
    }                                                                       \
    {                                                                       \
      const bf16x8* fa_ = fb8 + (size_t)(SVA) * 8 + swz;                    \
      __builtin_amdgcn_global_load_lds(                                     \
          (const __attribute__((address_space(1))) void*)fa_,               \
          (__attribute__((address_space(3))) void*)(smem + 24576 + (BUF) * 16384 + tid * 16), \
          16, 0, 0);                                                        \
      const bf16x8* fbp_ = fb8 + (size_t)(SVB) * 8 + swz;                   \
      __builtin_amdgcn_global_load_lds(                                     \
          (const __attribute__((address_space(1))) void*)fbp_,              \
          (__attribute__((address_space(3))) void*)(smem + 24576 + (BUF) * 16384 + 8192 + tid * 16), \
          16, 0, 0);                                                        \
    }                                                                       \
  }

#define CONSUME(BUF) {                                                     \
    const unsigned char* wp_ = smem + (BUF) * 8192;                        \
    const unsigned char* fp_ = smem + 24576 + (BUF) * 16384;               \
    bf16x8 W0 = *(const bf16x8*)(wp_ + 0 * 2048 + offW);                   \
    bf16x8 W1 = *(const bf16x8*)(wp_ + 1 * 2048 + offW);                   \
    bf16x8 W2 = *(const bf16x8*)(wp_ + 2 * 2048 + offW);                   \
    bf16x8 W3 = *(const bf16x8*)(wp_ + 3 * 2048 + offW);                   \
    bf16x8 A0 = *(const bf16x8*)(fp_ + offA0);                             \
    bf16x8 A1 = *(const bf16x8*)(fp_ + offA1);                             \
    accA0 = MFMA(A0, W0, accA0, 0, 0, 0);                                  \
    accA1 = MFMA(A0, W1, accA1, 0, 0, 0);                                  \
    accA2 = MFMA(A0, W2, accA2, 0, 0, 0);                                  \
    accA3 = MFMA(A0, W3, accA3, 0, 0, 0);                                  \
    accB0 = MFMA(A1, W0, accB0, 0, 0, 0);                                  \
    accB1 = MFMA(A1, W1, accB1, 0, 0, 0);                                  \
    accB2 = MFMA(A1, W2, accB2, 0, 0, 0);                                  \
    accB3 = MFMA(A1, W3, accB3, 0, 0, 0);                                  \
  }

#define WAITBAR(N)                                                          \
    SBR; asm volatile("s_waitcnt vmcnt(" #N ")" ::: "memory"); SBR;         \
    __builtin_amdgcn_s_barrier(); SBR;

  // prologue: stage slots 0,1; vmcnt(3) drains slot 0 (slot 1 in flight)
  STAGE(0, 0, row0g, row1g); SBR;
  STAGE(1, 1, i0a.x, i1a.x); SBR;
  WAITBAR(3);

  // round k: stage slot k+2 into buf (k+2)%3, consume buf k%3,
  // vmcnt(3) drains slot k+1 (slot k+2's 3 loads stay in flight), barrier.
  STAGE(2, 2, i0a.y, i1a.y);  SBR; CONSUME(0); WAITBAR(3);   // k=0
  STAGE(3, 0, i0a.z, i1a.z);  SBR; CONSUME(1); WAITBAR(3);   // k=1
  STAGE(4, 1, i0a.w, i1a.w);  SBR; CONSUME(2); WAITBAR(3);   // k=2
  STAGE(5, 2, i0b.x, i1b.x);  SBR; CONSUME(0); WAITBAR(3);   // k=3
  STAGE(6, 0, i0b.y, i1b.y);  SBR; CONSUME(1); WAITBAR(3);   // k=4
  STAGE(7, 1, i0b.z, i1b.z);  SBR; CONSUME(2); WAITBAR(3);   // k=5
  STAGE(8, 2, i0b.w, i1b.w);  SBR; CONSUME(0); WAITBAR(3);   // k=6
  STAGE(9, 0, i0c.x, i1c.x);  SBR; CONSUME(1); WAITBAR(3);   // k=7
  STAGE(10, 1, i0c.y, i1c.y); SBR; CONSUME(2); WAITBAR(3);   // k=8
  STAGE(11, 2, i0c.z, i1c.z); SBR; CONSUME(0); WAITBAR(3);   // k=9
  STAGE(12, 0, i0c.w, i1c.w); SBR; CONSUME(1); WAITBAR(3);   // k=10
  STAGE(13, 1, i0d.x, i1d.x); SBR; CONSUME(2); WAITBAR(3);   // k=11
  STAGE(14, 2, i0d.y, i1d.y); SBR; CONSUME(0); WAITBAR(3);   // k=12
  STAGE(15, 0, i0d.z, i1d.z); SBR; CONSUME(1); WAITBAR(3);   // k=13
  STAGE(16, 1, i0d.w, i1d.w); SBR; CONSUME(2); WAITBAR(3);   // k=14
  CONSUME(0); WAITBAR(0);                                    // k=15, drain 16
  CONSUME(1);                                                // k=16

#undef WAITBAR
#undef CONSUME
#undef STAGE
#undef MFMA
#undef SBR

  // reduce h-pairs through LDS (buffers dead), epilogue by h==0 waves.
  // region: [rg 0..3][cell 0..7][lane] f32x4 = 32KB.
  __syncthreads();
  if (h == 1) {
    float* rp = (float*)smem + rg * 2048 + lane * 4;
    *(f32x4*)(rp + 0 * 256) = accA0;
    *(f32x4*)(rp + 1 * 256) = accA1;
    *(f32x4*)(rp + 2 * 256) = accA2;
    *(f32x4*)(rp + 3 * 256) = accA3;
    *(f32x4*)(rp + 4 * 256) = accB0;
    *(f32x4*)(rp + 5 * 256) = accB1;
    *(f32x4*)(rp + 6 * 256) = accB2;
    *(f32x4*)(rp + 7 * 256) = accB3;
  }
  __syncthreads();
  if (h == 0) {
    const float* rp = (const float*)smem + rg * 2048 + lane * 4;
    accA0 += *(const f32x4*)(rp + 0 * 256);
    accA1 += *(const f32x4*)(rp + 1 * 256);
    accA2 += *(const f32x4*)(rp + 2 * 256);
    accA3 += *(const f32x4*)(rp + 3 * 256);
    accB0 += *(const f32x4*)(rp + 4 * 256);
    accB1 += *(const f32x4*)(rp + 5 * 256);
    accB2 += *(const f32x4*)(rp + 6 * 256);
    accB3 += *(const f32x4*)(rp + 7 * 256);

    const float bv0 = bias[lm];
    const float bv1 = bias[16 + lm];
    const float bv2 = bias[32 + lm];
    const float bv3 = bias[48 + lm];
    float* op = out + (size_t)b * NV * 64;
    #pragma unroll
    for (int mt = 0; mt < 2; ++mt) {
      const int gv = rbase + rg * 32 + mt * 16 + lk * 4;
      #pragma unroll
      for (int r = 0; r < 4; ++r) {
        float* orow = op + (size_t)(gv + r) * 64;
        if (mt == 0) {
          orow[lm]      = fmaxf(accA0[r] + bv0, 0.f);
          orow[16 + lm] = fmaxf(accA1[r] + bv1, 0.f);
          orow[32 + lm] = fmaxf(accA2[r] + bv2, 0.f);
          orow[48 + lm] = fmaxf(accA3[r] + bv3, 0.f);
        } else {
          orow[lm]      = fmaxf(accB0[r] + bv0, 0.f);
          orow[16 + lm] = fmaxf(accB1[r] + bv1, 0.f);
          orow[32 + lm] = fmaxf(accB2[r] + bv2, 0.f);
          orow[48 + lm] = fmaxf(accB3[r] + bv3, 0.f);
        }
      }
    }
  }
}

extern "C" void kernel_launch(void* const* d_in, const int* in_sizes, int n_in,
                              void* d_out, int out_size, void* d_ws, size_t ws_size,
                              hipStream_t stream) {
  const int* nbr = (const int*)d_in[0];
  // d_in[1] = vertices (unused by the reference computation)
  const float* fm = (const float*)d_in[2];
  const float* w = (const float*)d_in[3];
  const float* bias = (const float*)d_in[4];
  float* out = (float*)d_out;

  unsigned short* fmb = (unsigned short*)d_ws;          // 8*4096*64 bf16 = 4 MB
  unsigned short* wb = fmb + (size_t)8 * NV * 64;       // 17*64*64 bf16

  prep<<<1296, 256, 0, stream>>>(fm, w, fmb, wb);
  conv_main<<<256, 512, 0, stream>>>(nbr, fmb, wb, bias, out);
}

// Round 18
// 19.243 us; speedup vs baseline: 1.1957x; 1.0265x over previous
//
#include <hip/hip_runtime.h>
#include <stdint.h>

#define NV 4096

typedef __attribute__((ext_vector_type(8))) short bf16x8;
typedef __attribute__((ext_vector_type(4))) float f32x4;

__device__ __forceinline__ unsigned short f2bf(float f) {
  union { float f; unsigned int u; } v; v.f = f;
  unsigned int r = v.u + 0x7FFF + ((v.u >> 16) & 1);  // RNE
  return (unsigned short)(r >> 16);
}

// fused prep: blocks 0..1023 convert feature_map f32->bf16 (8 elems/thread);
// blocks 1024..1295 permute weights (64 x 1088, f=c*17+k) -> Wb[k][o][c] bf16.
__global__ __launch_bounds__(256)
void prep(const float* __restrict__ fm, const float* __restrict__ w,
          unsigned short* __restrict__ fmb, unsigned short* __restrict__ wb) {
  int blk = blockIdx.x;
  if (blk < 1024) {
    int i = (blk * 256 + threadIdx.x) * 8;
    float4 v0 = *(const float4*)(fm + i);
    float4 v1 = *(const float4*)(fm + i + 4);
    ushort4 o0, o1;
    o0.x = f2bf(v0.x); o0.y = f2bf(v0.y); o0.z = f2bf(v0.z); o0.w = f2bf(v0.w);
    o1.x = f2bf(v1.x); o1.y = f2bf(v1.y); o1.z = f2bf(v1.z); o1.w = f2bf(v1.w);
    *(ushort4*)(fmb + i) = o0;
    *(ushort4*)(fmb + i + 4) = o1;
  } else {
    int t = (blk - 1024) * 256 + threadIdx.x;  // 0..69631 (= 17*64*64)
    int c = t & 63;
    int o = (t >> 6) & 63;
    int k = t >> 12;
    wb[t] = f2bf(w[o * 1088 + c * 17 + k]);
  }
}

// R17 structure with PAIRWISE-MERGED rounds (BK=128): each round stages a
// PAIR of slots and consumes a pair -> 10 barriers instead of 17, deeper
// MFMA clusters.  6 slot buffers (W 48KB + F 96KB = 144KB), 1 block/CU.
// Block = 512 thr = 8 waves = 4 row-groups x 2 ch-halves; 128 rows; grid 256.
__global__ __launch_bounds__(512, 1)
void conv_main(const int* __restrict__ nbr, const unsigned short* __restrict__ fmb,
               const unsigned short* __restrict__ wb, const float* __restrict__ bias,
               float* __restrict__ out) {
  __shared__ unsigned char smem[147456];  // W: 6x8KB @0, F: 6x16KB @49152

  const int bid = blockIdx.x;
  const int b = bid & 7;               // batch == XCD (256%8==0, bijective)
  const int tile = bid >> 3;           // 0..31
  const int tid = threadIdx.x;         // 0..511
  const int lane = tid & 63;
  const int lm = lane & 15;
  const int lk = lane >> 4;
  const int w8 = tid >> 6;             // wave 0..7
  const int rg = w8 >> 1;              // row-group 0..3 (32 rows)
  const int h = w8 & 1;                // channel half

  const int rbase = tile * 128;
  const bf16x8* fb8 = (const bf16x8*)(fmb + (size_t)b * NV * 64);

  // staging identity: thread t stages F granule (t&7) of rows (t>>3) and
  // (t>>3)+64; 8 consecutive lanes cover one row's 128B contiguously.
  const int r0 = tid >> 3;             // 0..63
  const int c8 = tid & 7;
  const int swz = c8 ^ (r0 & 7);       // source-granule swizzle
  const int row0g = rbase + r0;
  const int row1g = rbase + r0 + 64;

  const int4* q0 = (const int4*)(nbr + ((size_t)b * NV + row0g) * 16);
  const int4* q1 = (const int4*)(nbr + ((size_t)b * NV + row1g) * 16);
  const int4 i0a = q0[0], i0b = q0[1], i0c = q0[2], i0d = q0[3];
  const int4 i1a = q1[0], i1b = q1[1], i1c = q1[2], i1d = q1[3];

  // consumer read offsets (R17-verified math)
  const int fsl = h * 4 + lk;
  const int offW = lm * 128 + ((fsl ^ (lm & 7)) << 4);
  const int rowL0 = rg * 32 + lm;
  const int rowL1 = rg * 32 + 16 + lm;
  const int offA0 = rowL0 * 128 + ((fsl ^ (rowL0 & 7)) << 4);
  const int offA1 = rowL1 * 128 + ((fsl ^ (rowL1 & 7)) << 4);

  f32x4 accA0{0,0,0,0}, accA1{0,0,0,0}, accA2{0,0,0,0}, accA3{0,0,0,0};
  f32x4 accB0{0,0,0,0}, accB1{0,0,0,0}, accB2{0,0,0,0}, accB3{0,0,0,0};

#define SBR __builtin_amdgcn_sched_barrier(0)
#define MFMA __builtin_amdgcn_mfma_f32_16x16x32_bf16

  // 3 gloads/thread per slot: 1 W granule + 2 F rows (sources pre-swizzled)
#define STAGE(SLOT, BUF, SVA, SVB) {                                        \
    {                                                                       \
      int o_ = (tid >> 3) & 63, s_ = tid & 7;                               \
      const unsigned short* ws_ =                                           \
          wb + (SLOT) * 4096 + o_ * 64 + ((s_ ^ (o_ & 7)) << 3);            \
      __builtin_amdgcn_global_load_lds(                                     \
          (const __attribute__((address_space(1))) void*)ws_,               \
          (__attribute__((address_space(3))) void*)(smem + (BUF) * 8192 + tid * 16), \
          16, 0, 0);                                                        \
    }                                                                       \
    {                                                                       \
      const bf16x8* fa_ = fb8 + (size_t)(SVA) * 8 + swz;                    \
      __builtin_amdgcn_global_load_lds(                                     \
          (const __attribute__((address_space(1))) void*)fa_,               \
          (__attribute__((address_space(3))) void*)(smem + 49152 + (BUF) * 16384 + tid * 16), \
          16, 0, 0);                                                        \
      const bf16x8* fbp_ = fb8 + (size_t)(SVB) * 8 + swz;                   \
      __builtin_amdgcn_global_load_lds(                                     \
          (const __attribute__((address_space(1))) void*)fbp_,              \
          (__attribute__((address_space(3))) void*)(smem + 49152 + (BUF) * 16384 + 8192 + tid * 16), \
          16, 0, 0);                                                        \
    }                                                                       \
  }

#define CONSUME(BUF) {                                                     \
    const unsigned char* wp_ = smem + (BUF) * 8192;                        \
    const unsigned char* fp_ = smem + 49152 + (BUF) * 16384;               \
    bf16x8 W0 = *(const bf16x8*)(wp_ + 0 * 2048 + offW);                   \
    bf16x8 W1 = *(const bf16x8*)(wp_ + 1 * 2048 + offW);                   \
    bf16x8 W2 = *(const bf16x8*)(wp_ + 2 * 2048 + offW);                   \
    bf16x8 W3 = *(const bf16x8*)(wp_ + 3 * 2048 + offW);                   \
    bf16x8 A0 = *(const bf16x8*)(fp_ + offA0);                             \
    bf16x8 A1 = *(const bf16x8*)(fp_ + offA1);                             \
    accA0 = MFMA(A0, W0, accA0, 0, 0, 0);                                  \
    accA1 = MFMA(A0, W1, accA1, 0, 0, 0);                                  \
    accA2 = MFMA(A0, W2, accA2, 0, 0, 0);                                  \
    accA3 = MFMA(A0, W3, accA3, 0, 0, 0);                                  \
    accB0 = MFMA(A1, W0, accB0, 0, 0, 0);                                  \
    accB1 = MFMA(A1, W1, accB1, 0, 0, 0);                                  \
    accB2 = MFMA(A1, W2, accB2, 0, 0, 0);                                  \
    accB3 = MFMA(A1, W3, accB3, 0, 0, 0);                                  \
  }

#define WAITBAR(N)                                                          \
    SBR; asm volatile("s_waitcnt vmcnt(" #N ")" ::: "memory"); SBR;         \
    __builtin_amdgcn_s_barrier(); SBR;

  // prologue: stage pairs (0,1) and (2,3); drain pair 0 (pair 1 in flight)
  STAGE(0, 0, row0g, row1g);   STAGE(1, 1, i0a.x, i1a.x);  SBR;
  STAGE(2, 2, i0a.y, i1a.y);   STAGE(3, 3, i0a.z, i1a.z);  SBR;
  WAITBAR(6);

  // round j: stage pair j+2 (6 loads/thread), consume pair j, vmcnt(6)
  // drains pair j+1 (pair j+2 stays in flight), barrier.
  STAGE(4, 4, i0a.w, i1a.w);   STAGE(5, 5, i0b.x, i1b.x);  SBR;
  CONSUME(0); CONSUME(1);      WAITBAR(6);                       // j=0
  STAGE(6, 0, i0b.y, i1b.y);   STAGE(7, 1, i0b.z, i1b.z);  SBR;
  CONSUME(2); CONSUME(3);      WAITBAR(6);                       // j=1
  STAGE(8, 2, i0b.w, i1b.w);   STAGE(9, 3, i0c.x, i1c.x);  SBR;
  CONSUME(4); CONSUME(5);      WAITBAR(6);                       // j=2
  STAGE(10, 4, i0c.y, i1c.y);  STAGE(11, 5, i0c.z, i1c.z); SBR;
  CONSUME(0); CONSUME(1);      WAITBAR(6);                       // j=3
  STAGE(12, 0, i0c.w, i1c.w);  STAGE(13, 1, i0d.x, i1d.x); SBR;
  CONSUME(2); CONSUME(3);      WAITBAR(6);                       // j=4
  STAGE(14, 2, i0d.y, i1d.y);  STAGE(15, 3, i0d.z, i1d.z); SBR;
  CONSUME(4); CONSUME(5);      WAITBAR(6);                       // j=5
  STAGE(16, 4, i0d.w, i1d.w);  SBR;
  CONSUME(0); CONSUME(1);      WAITBAR(3);                       // j=6 (drains 14,15)
  CONSUME(2); CONSUME(3);      WAITBAR(0);                       // drains 16
  CONSUME(4);                                                    // slot 16

#undef WAITBAR
#undef CONSUME
#undef STAGE
#undef MFMA
#undef SBR

  // reduce h-pairs through LDS (buffers dead), epilogue by h==0 waves.
  // region: [rg 0..3][cell 0..7][lane] f32x4 = 32KB.
  __syncthreads();
  if (h == 1) {
    float* rp = (float*)smem + rg * 2048 + lane * 4;
    *(f32x4*)(rp + 0 * 256) = accA0;
    *(f32x4*)(rp + 1 * 256) = accA1;
    *(f32x4*)(rp + 2 * 256) = accA2;
    *(f32x4*)(rp + 3 * 256) = accA3;
    *(f32x4*)(rp + 4 * 256) = accB0;
    *(f32x4*)(rp + 5 * 256) = accB1;
    *(f32x4*)(rp + 6 * 256) = accB2;
    *(f32x4*)(rp + 7 * 256) = accB3;
  }
  __syncthreads();
  if (h == 0) {
    const float* rp = (const float*)smem + rg * 2048 + lane * 4;
    accA0 += *(const f32x4*)(rp + 0 * 256);
    accA1 += *(const f32x4*)(rp + 1 * 256);
    accA2 += *(const f32x4*)(rp + 2 * 256);
    accA3 += *(const f32x4*)(rp + 3 * 256);
    accB0 += *(const f32x4*)(rp + 4 * 256);
    accB1 += *(const f32x4*)(rp + 5 * 256);
    accB2 += *(const f32x4*)(rp + 6 * 256);
    accB3 += *(const f32x4*)(rp + 7 * 256);

    const float bv0 = bias[lm];
    const float bv1 = bias[16 + lm];
    const float bv2 = bias[32 + lm];
    const float bv3 = bias[48 + lm];
    float* op = out + (size_t)b * NV * 64;
    #pragma unroll
    for (int mt = 0; mt < 2; ++mt) {
      const int gv = rbase + rg * 32 + mt * 16 + lk * 4;
      #pragma unroll
      for (int r = 0; r < 4; ++r) {
        float* orow = op + (size_t)(gv + r) * 64;
        if (mt == 0) {
          orow[lm]      = fmaxf(accA0[r] + bv0, 0.f);
          orow[16 + lm] = fmaxf(accA1[r] + bv1, 0.f);
          orow[32 + lm] = fmaxf(accA2[r] + bv2, 0.f);
          orow[48 + lm] = fmaxf(accA3[r] + bv3, 0.f);
        } else {
          orow[lm]      = fmaxf(accB0[r] + bv0, 0.f);
          orow[16 + lm] = fmaxf(accB1[r] + bv1, 0.f);
          orow[32 + lm] = fmaxf(accB2[r] + bv2, 0.f);
          orow[48 + lm] = fmaxf(accB3[r] + bv3, 0.f);
        }
      }
    }
  }
}

extern "C" void kernel_launch(void* const* d_in, const int* in_sizes, int n_in,
                              void* d_out, int out_size, void* d_ws, size_t ws_size,
                              hipStream_t stream) {
  const int* nbr = (const int*)d_in[0];
  // d_in[1] = vertices (unused by the reference computation)
  const float* fm = (const float*)d_in[2];
  const float* w = (const float*)d_in[3];
  const float* bias = (const float*)d_in[4];
  float* out = (float*)d_out;

  unsigned short* fmb = (unsigned short*)d_ws;          // 8*4096*64 bf16 = 4 MB
  unsigned short* wb = fmb + (size_t)8 * NV * 64;       // 17*64*64 bf16

  prep<<<1296, 256, 0, stream>>>(fm, w, fmb, wb);
  conv_main<<<256, 512, 0, stream>>>(nbr, fmb, wb, bias, out);
}

// Round 19
// 19.111 us; speedup vs baseline: 1.2040x; 1.0069x over previous
//
#include <hip/hip_runtime.h>
#include <stdint.h>

#define NV 4096

typedef __attribute__((ext_vector_type(8))) short bf16x8;
typedef __attribute__((ext_vector_type(4))) float f32x4;

__device__ __forceinline__ unsigned short f2bf(float f) {
  union { float f; unsigned int u; } v; v.f = f;
  unsigned int r = v.u + 0x7FFF + ((v.u >> 16) & 1);  // RNE
  return (unsigned short)(r >> 16);
}

// fused prep: blocks 0..1023 convert feature_map f32->bf16 (8 elems/thread);
// blocks 1024..1295 permute weights (64 x 1088, f=c*17+k) -> Wb[k][o][c] bf16.
__global__ __launch_bounds__(256)
void prep(const float* __restrict__ fm, const float* __restrict__ w,
          unsigned short* __restrict__ fmb, unsigned short* __restrict__ wb) {
  int blk = blockIdx.x;
  if (blk < 1024) {
    int i = (blk * 256 + threadIdx.x) * 8;
    float4 v0 = *(const float4*)(fm + i);
    float4 v1 = *(const float4*)(fm + i + 4);
    ushort4 o0, o1;
    o0.x = f2bf(v0.x); o0.y = f2bf(v0.y); o0.z = f2bf(v0.z); o0.w = f2bf(v0.w);
    o1.x = f2bf(v1.x); o1.y = f2bf(v1.y); o1.z = f2bf(v1.z); o1.w = f2bf(v1.w);
    *(ushort4*)(fmb + i) = o0;
    *(ushort4*)(fmb + i + 4) = o1;
  } else {
    int t = (blk - 1024) * 256 + threadIdx.x;  // 0..69631 (= 17*64*64)
    int c = t & 63;
    int o = (t >> 6) & 63;
    int k = t >> 12;
    wb[t] = f2bf(w[o * 1088 + c * 17 + k]);
  }
}

// R18 (pairwise-merged rounds, BK=128) + s_setprio(1) around the 16-MFMA
// consume clusters (T5: 8 waves in role-diverse phases w/ counted vmcnt).
// 6 slot buffers (W 48KB + F 96KB = 144KB), 1 block/CU.
// Block = 512 thr = 8 waves = 4 row-groups x 2 ch-halves; 128 rows; grid 256.
__global__ __launch_bounds__(512, 1)
void conv_main(const int* __restrict__ nbr, const unsigned short* __restrict__ fmb,
               const unsigned short* __restrict__ wb, const float* __restrict__ bias,
               float* __restrict__ out) {
  __shared__ unsigned char smem[147456];  // W: 6x8KB @0, F: 6x16KB @49152

  const int bid = blockIdx.x;
  const int b = bid & 7;               // batch == XCD (256%8==0, bijective)
  const int tile = bid >> 3;           // 0..31
  const int tid = threadIdx.x;         // 0..511
  const int lane = tid & 63;
  const int lm = lane & 15;
  const int lk = lane >> 4;
  const int w8 = tid >> 6;             // wave 0..7
  const int rg = w8 >> 1;              // row-group 0..3 (32 rows)
  const int h = w8 & 1;                // channel half

  const int rbase = tile * 128;
  const bf16x8* fb8 = (const bf16x8*)(fmb + (size_t)b * NV * 64);

  // staging identity: thread t stages F granule (t&7) of rows (t>>3) and
  // (t>>3)+64; 8 consecutive lanes cover one row's 128B contiguously.
  const int r0 = tid >> 3;             // 0..63
  const int c8 = tid & 7;
  const int swz = c8 ^ (r0 & 7);       // source-granule swizzle
  const int row0g = rbase + r0;
  const int row1g = rbase + r0 + 64;

  const int4* q0 = (const int4*)(nbr + ((size_t)b * NV + row0g) * 16);
  const int4* q1 = (const int4*)(nbr + ((size_t)b * NV + row1g) * 16);
  const int4 i0a = q0[0], i0b = q0[1], i0c = q0[2], i0d = q0[3];
  const int4 i1a = q1[0], i1b = q1[1], i1c = q1[2], i1d = q1[3];

  // consumer read offsets (R17-verified math)
  const int fsl = h * 4 + lk;
  const int offW = lm * 128 + ((fsl ^ (lm & 7)) << 4);
  const int rowL0 = rg * 32 + lm;
  const int rowL1 = rg * 32 + 16 + lm;
  const int offA0 = rowL0 * 128 + ((fsl ^ (rowL0 & 7)) << 4);
  const int offA1 = rowL1 * 128 + ((fsl ^ (rowL1 & 7)) << 4);

  f32x4 accA0{0,0,0,0}, accA1{0,0,0,0}, accA2{0,0,0,0}, accA3{0,0,0,0};
  f32x4 accB0{0,0,0,0}, accB1{0,0,0,0}, accB2{0,0,0,0}, accB3{0,0,0,0};

#define SBR __builtin_amdgcn_sched_barrier(0)
#define MFMA __builtin_amdgcn_mfma_f32_16x16x32_bf16

  // 3 gloads/thread per slot: 1 W granule + 2 F rows (sources pre-swizzled)
#define STAGE(SLOT, BUF, SVA, SVB) {                                        \
    {                                                                       \
      int o_ = (tid >> 3) & 63, s_ = tid & 7;                               \
      const unsigned short* ws_ =                                           \
          wb + (SLOT) * 4096 + o_ * 64 + ((s_ ^ (o_ & 7)) << 3);            \
      __builtin_amdgcn_global_load_lds(                                     \
          (const __attribute__((address_space(1))) void*)ws_,               \
          (__attribute__((address_space(3))) void*)(smem + (BUF) * 8192 + tid * 16), \
          16, 0, 0);                                                        \
    }                                                                       \
    {                                                                       \
      const bf16x8* fa_ = fb8 + (size_t)(SVA) * 8 + swz;                    \
      __builtin_amdgcn_global_load_lds(                                     \
          (const __attribute__((address_space(1))) void*)fa_,               \
          (__attribute__((address_space(3))) void*)(smem + 49152 + (BUF) * 16384 + tid * 16), \
          16, 0, 0);                                                        \
      const bf16x8* fbp_ = fb8 + (size_t)(SVB) * 8 + swz;                   \
      __builtin_amdgcn_global_load_lds(                                     \
          (const __attribute__((address_space(1))) void*)fbp_,              \
          (__attribute__((address_space(3))) void*)(smem + 49152 + (BUF) * 16384 + 8192 + tid * 16), \
          16, 0, 0);                                                        \
    }                                                                       \
  }

#define CONSUME(BUF) {                                                     \
    const unsigned char* wp_ = smem + (BUF) * 8192;                        \
    const unsigned char* fp_ = smem + 49152 + (BUF) * 16384;               \
    bf16x8 W0 = *(const bf16x8*)(wp_ + 0 * 2048 + offW);                   \
    bf16x8 W1 = *(const bf16x8*)(wp_ + 1 * 2048 + offW);                   \
    bf16x8 W2 = *(const bf16x8*)(wp_ + 2 * 2048 + offW);                   \
    bf16x8 W3 = *(const bf16x8*)(wp_ + 3 * 2048 + offW);                   \
    bf16x8 A0 = *(const bf16x8*)(fp_ + offA0);                             \
    bf16x8 A1 = *(const bf16x8*)(fp_ + offA1);                             \
    __builtin_amdgcn_s_setprio(1);                                         \
    accA0 = MFMA(A0, W0, accA0, 0, 0, 0);                                  \
    accA1 = MFMA(A0, W1, accA1, 0, 0, 0);                                  \
    accA2 = MFMA(A0, W2, accA2, 0, 0, 0);                                  \
    accA3 = MFMA(A0, W3, accA3, 0, 0, 0);                                  \
    accB0 = MFMA(A1, W0, accB0, 0, 0, 0);                                  \
    accB1 = MFMA(A1, W1, accB1, 0, 0, 0);                                  \
    accB2 = MFMA(A1, W2, accB2, 0, 0, 0);                                  \
    accB3 = MFMA(A1, W3, accB3, 0, 0, 0);                                  \
    __builtin_amdgcn_s_setprio(0);                                         \
  }

#define WAITBAR(N)                                                          \
    SBR; asm volatile("s_waitcnt vmcnt(" #N ")" ::: "memory"); SBR;         \
    __builtin_amdgcn_s_barrier(); SBR;

  // prologue: stage pairs (0,1) and (2,3); drain pair 0 (pair 1 in flight)
  STAGE(0, 0, row0g, row1g);   STAGE(1, 1, i0a.x, i1a.x);  SBR;
  STAGE(2, 2, i0a.y, i1a.y);   STAGE(3, 3, i0a.z, i1a.z);  SBR;
  WAITBAR(6);

  // round j: stage pair j+2 (6 loads/thread), consume pair j, vmcnt(6)
  // drains pair j+1 (pair j+2 stays in flight), barrier.
  STAGE(4, 4, i0a.w, i1a.w);   STAGE(5, 5, i0b.x, i1b.x);  SBR;
  CONSUME(0); CONSUME(1);      WAITBAR(6);                       // j=0
  STAGE(6, 0, i0b.y, i1b.y);   STAGE(7, 1, i0b.z, i1b.z);  SBR;
  CONSUME(2); CONSUME(3);      WAITBAR(6);                       // j=1
  STAGE(8, 2, i0b.w, i1b.w);   STAGE(9, 3, i0c.x, i1c.x);  SBR;
  CONSUME(4); CONSUME(5);      WAITBAR(6);                       // j=2
  STAGE(10, 4, i0c.y, i1c.y);  STAGE(11, 5, i0c.z, i1c.z); SBR;
  CONSUME(0); CONSUME(1);      WAITBAR(6);                       // j=3
  STAGE(12, 0, i0c.w, i1c.w);  STAGE(13, 1, i0d.x, i1d.x); SBR;
  CONSUME(2); CONSUME(3);      WAITBAR(6);                       // j=4
  STAGE(14, 2, i0d.y, i1d.y);  STAGE(15, 3, i0d.z, i1d.z); SBR;
  CONSUME(4); CONSUME(5);      WAITBAR(6);                       // j=5
  STAGE(16, 4, i0d.w, i1d.w);  SBR;
  CONSUME(0); CONSUME(1);      WAITBAR(3);                       // j=6 (drains 14,15)
  CONSUME(2); CONSUME(3);      WAITBAR(0);                       // drains 16
  CONSUME(4);                                                    // slot 16

#undef WAITBAR
#undef CONSUME
#undef STAGE
#undef MFMA
#undef SBR

  // reduce h-pairs through LDS (buffers dead), epilogue by h==0 waves.
  // region: [rg 0..3][cell 0..7][lane] f32x4 = 32KB.
  __syncthreads();
  if (h == 1) {
    float* rp = (float*)smem + rg * 2048 + lane * 4;
    *(f32x4*)(rp + 0 * 256) = accA0;
    *(f32x4*)(rp + 1 * 256) = accA1;
    *(f32x4*)(rp + 2 * 256) = accA2;
    *(f32x4*)(rp + 3 * 256) = accA3;
    *(f32x4*)(rp + 4 * 256) = accB0;
    *(f32x4*)(rp + 5 * 256) = accB1;
    *(f32x4*)(rp + 6 * 256) = accB2;
    *(f32x4*)(rp + 7 * 256) = accB3;
  }
  __syncthreads();
  if (h == 0) {
    const float* rp = (const float*)smem + rg * 2048 + lane * 4;
    accA0 += *(const f32x4*)(rp + 0 * 256);
    accA1 += *(const f32x4*)(rp + 1 * 256);
    accA2 += *(const f32x4*)(rp + 2 * 256);
    accA3 += *(const f32x4*)(rp + 3 * 256);
    accB0 += *(const f32x4*)(rp + 4 * 256);
    accB1 += *(const f32x4*)(rp + 5 * 256);
    accB2 += *(const f32x4*)(rp + 6 * 256);
    accB3 += *(const f32x4*)(rp + 7 * 256);

    const float bv0 = bias[lm];
    const float bv1 = bias[16 + lm];
    const float bv2 = bias[32 + lm];
    const float bv3 = bias[48 + lm];
    float* op = out + (size_t)b * NV * 64;
    #pragma unroll
    for (int mt = 0; mt < 2; ++mt) {
      const int gv = rbase + rg * 32 + mt * 16 + lk * 4;
      #pragma unroll
      for (int r = 0; r < 4; ++r) {
        float* orow = op + (size_t)(gv + r) * 64;
        if (mt == 0) {
          orow[lm]      = fmaxf(accA0[r] + bv0, 0.f);
          orow[16 + lm] = fmaxf(accA1[r] + bv1, 0.f);
          orow[32 + lm] = fmaxf(accA2[r] + bv2, 0.f);
          orow[48 + lm] = fmaxf(accA3[r] + bv3, 0.f);
        } else {
          orow[lm]      = fmaxf(accB0[r] + bv0, 0.f);
          orow[16 + lm] = fmaxf(accB1[r] + bv1, 0.f);
          orow[32 + lm] = fmaxf(accB2[r] + bv2, 0.f);
          orow[48 + lm] = fmaxf(accB3[r] + bv3, 0.f);
        }
      }
    }
  }
}

extern "C" void kernel_launch(void* const* d_in, const int* in_sizes, int n_in,
                              void* d_out, int out_size, void* d_ws, size_t ws_size,
                              hipStream_t stream) {
  const int* nbr = (const int*)d_in[0];
  // d_in[1] = vertices (unused by the reference computation)
  const float* fm = (const float*)d_in[2];
  const float* w = (const float*)d_in[3];
  const float* bias = (const float*)d_in[4];
  float* out = (float*)d_out;

  unsigned short* fmb = (unsigned short*)d_ws;          // 8*4096*64 bf16 = 4 MB
  unsigned short* wb = fmb + (size_t)8 * NV * 64;       // 17*64*64 bf16

  prep<<<1296, 256, 0, stream>>>(fm, w, fmb, wb);
  conv_main<<<256, 512, 0, stream>>>(nbr, fmb, wb, bias, out);
}